// Round 1
// baseline (282.498 us; speedup 1.0000x reference)
//
#include <hip/hip_runtime.h>

typedef unsigned int uint;
typedef unsigned short ushort;
typedef __attribute__((ext_vector_type(8))) short bf16x8;
typedef __attribute__((ext_vector_type(4))) float f32x4;
typedef __attribute__((ext_vector_type(4))) float float4v;
typedef __attribute__((ext_vector_type(4))) ushort ushort4v;

#define B_ 4
#define S_ 2048
#define D_ 1024
#define MTOT (B_ * S_)   // 8192

__device__ __forceinline__ ushort f2bf(float f) {
    uint u = __builtin_bit_cast(uint, f);
    u = (u + 0x7FFFu + ((u >> 16) & 1u)) >> 16;   // RNE
    return (ushort)u;
}
__device__ __forceinline__ float bf2f(ushort h) {
    uint u = ((uint)h) << 16;
    return __builtin_bit_cast(float, u);
}

__device__ __forceinline__ void gload_lds16(const ushort* g, ushort* l) {
    __builtin_amdgcn_global_load_lds(
        (const __attribute__((address_space(1))) void*)g,
        (__attribute__((address_space(3))) void*)l, 16, 0, 0);
}

// ---------------- cast kernel: fp32 -> bf16, 4 elems/thread ----------------
__global__ void cast_f32_to_bf16(const float* __restrict__ src,
                                 ushort* __restrict__ dst, int n4) {
    int i = blockIdx.x * blockDim.x + threadIdx.x;
    int stride = gridDim.x * blockDim.x;
    for (; i < n4; i += stride) {
        float4v f = *(const float4v*)(src + (size_t)i * 4);
        ushort4v h;
        h.x = f2bf(f.x); h.y = f2bf(f.y); h.z = f2bf(f.z); h.w = f2bf(f.w);
        *(ushort4v*)(dst + (size_t)i * 4) = h;
    }
}

// ---------------- GEMM core: 128x128 tile, BK=32, 256 thr / 4 waves -------
// A tile [128][32] bf16 (K-contiguous), B tile [128][32] bf16 (K-contiguous,
// i.e. B is the transposed operand). C = A * B^T. LDS linear, global_load_lds.
__device__ __forceinline__ void stage32(const ushort* __restrict__ Ag, int lda,
                                        const ushort* __restrict__ Bg, int ldb,
                                        int k0, ushort* smbuf, int t) {
#pragma unroll
    for (int i = 0; i < 2; ++i) {
        int e = i * 2048 + t * 8;
        int r = e >> 5, c = e & 31;
        int ldsbase = i * 2048 + (t & 192) * 8;     // wave-uniform
        gload_lds16(Ag + (size_t)r * lda + (k0 + c), smbuf + ldsbase);
        gload_lds16(Bg + (size_t)r * ldb + (k0 + c), smbuf + 4096 + ldsbase);
    }
}

__device__ __forceinline__ void mm_acc(const ushort* __restrict__ Ag, int lda,
                                       const ushort* __restrict__ Bg, int ldb,
                                       int nk, ushort* sm, f32x4 acc[4][4]) {
    const int t = threadIdx.x;
    const int lane = t & 63;
    const int wid = t >> 6;
    const int wr = wid >> 1, wc = wid & 1;
    const int ro = lane & 15, ko = (lane >> 4) << 3;

    stage32(Ag, lda, Bg, ldb, 0, sm, t);
    __syncthreads();
    int cur = 0;
    for (int ks = 0; ks < nk; ++ks) {
        if (ks + 1 < nk)
            stage32(Ag, lda, Bg, ldb, (ks + 1) * 32, sm + (cur ^ 1) * 8192, t);
        const ushort* As = sm + cur * 8192;
        const ushort* Bs = As + 4096;
        bf16x8 af[4], bfr[4];
#pragma unroll
        for (int i = 0; i < 4; ++i)
            af[i] = *(const bf16x8*)(As + (wr * 64 + i * 16 + ro) * 32 + ko);
#pragma unroll
        for (int j = 0; j < 4; ++j)
            bfr[j] = *(const bf16x8*)(Bs + (wc * 64 + j * 16 + ro) * 32 + ko);
#pragma unroll
        for (int i = 0; i < 4; ++i)
#pragma unroll
            for (int j = 0; j < 4; ++j)
                acc[i][j] = __builtin_amdgcn_mfma_f32_16x16x32_bf16(
                    af[i], bfr[j], acc[i][j], 0, 0, 0);
        __syncthreads();
        cur ^= 1;
    }
}

// ---------------- QKV projection: C[m][n] = x[m][:] . W[n][:] -------------
// z=0 -> Q (scaled 1/32), z=1 -> K, z=2 -> V stored transposed per batch.
__global__ __launch_bounds__(256) void gemm_qkv(
    const ushort* __restrict__ xb, const ushort* __restrict__ Wb,
    ushort* __restrict__ Qb, ushort* __restrict__ Kb, ushort* __restrict__ Vt) {
    __shared__ ushort sm[2 * 8192];
    int bn = blockIdx.x, bm = blockIdx.y, z = blockIdx.z;
    f32x4 acc[4][4] = {};
    const ushort* Ag = xb + (size_t)bm * 128 * D_;
    const ushort* Bg = Wb + (size_t)z * D_ * D_ + (size_t)bn * 128 * D_;
    mm_acc(Ag, D_, Bg, D_, D_ / 32, sm, acc);

    const int lane = threadIdx.x & 63;
    const int wid = threadIdx.x >> 6;
    const int wr = wid >> 1, wc = wid & 1;
    const float scale = (z == 0) ? 0.03125f : 1.0f;
#pragma unroll
    for (int i = 0; i < 4; ++i)
#pragma unroll
        for (int j = 0; j < 4; ++j)
#pragma unroll
            for (int q = 0; q < 4; ++q) {
                int row = wr * 64 + i * 16 + ((lane >> 4) << 2) + q;
                int col = bn * 128 + wc * 64 + j * 16 + (lane & 15);
                int grow = bm * 128 + row;
                ushort val = f2bf(acc[i][j][q] * scale);
                if (z == 0) {
                    Qb[(size_t)grow * D_ + col] = val;
                } else if (z == 1) {
                    Kb[(size_t)grow * D_ + col] = val;
                } else {
                    int b = grow >> 11, s = grow & 2047;
                    Vt[(size_t)b * D_ * S_ + (size_t)col * S_ + s] = val;
                }
            }
}

// ---------------- scores: S[b][m][n] = Q[b][m][:] . K[b][n][:] ------------
__global__ __launch_bounds__(256) void gemm_scores(
    const ushort* __restrict__ Qb, const ushort* __restrict__ Kb,
    ushort* __restrict__ Sb) {
    int bn = blockIdx.x, bm = blockIdx.y, b = blockIdx.z;
    if (bn > bm) return;                 // strictly-upper tiles never read
    __shared__ ushort sm[2 * 8192];
    f32x4 acc[4][4] = {};
    const ushort* Ag = Qb + (size_t)b * S_ * D_ + (size_t)bm * 128 * D_;
    const ushort* Bg = Kb + (size_t)b * S_ * D_ + (size_t)bn * 128 * D_;
    mm_acc(Ag, D_, Bg, D_, D_ / 32, sm, acc);

    const int lane = threadIdx.x & 63;
    const int wid = threadIdx.x >> 6;
    const int wr = wid >> 1, wc = wid & 1;
    ushort* Crow = Sb + (size_t)b * S_ * S_;
#pragma unroll
    for (int i = 0; i < 4; ++i)
#pragma unroll
        for (int j = 0; j < 4; ++j)
#pragma unroll
            for (int q = 0; q < 4; ++q) {
                int row = bm * 128 + wr * 64 + i * 16 + ((lane >> 4) << 2) + q;
                int col = bn * 128 + wc * 64 + j * 16 + (lane & 15);
                Crow[(size_t)row * S_ + col] = f2bf(acc[i][j][q]);
            }
}

// ---------------- causal row softmax, in place, bf16 ----------------------
__global__ __launch_bounds__(256) void softmax_causal(ushort* __restrict__ S) {
    int r = blockIdx.x;                  // 0..8191
    int b = r >> 11, rr = r & 2047;
    int L = ((rr >> 7) + 1) << 7;        // padded causal length (mult of 128)
    ushort* row = S + (size_t)b * S_ * S_ + (size_t)rr * S_;
    int t = threadIdx.x;
    int lane = t & 63, wid = t >> 6;
    int j0 = t * 8;
    bool act = j0 < L;

    float v[8];
    float mx = -1e30f;
    if (act) {
        bf16x8 raw = *(const bf16x8*)(row + j0);
#pragma unroll
        for (int e = 0; e < 8; ++e) {
            int col = j0 + e;
            float f = bf2f((ushort)raw[e]);
            v[e] = (col <= rr) ? f : -1e30f;
            mx = fmaxf(mx, v[e]);
        }
    }
    __shared__ float redm[4], reds[4];
#pragma unroll
    for (int off = 32; off >= 1; off >>= 1) mx = fmaxf(mx, __shfl_xor(mx, off));
    if (lane == 0) redm[wid] = mx;
    __syncthreads();
    float m2 = fmaxf(fmaxf(redm[0], redm[1]), fmaxf(redm[2], redm[3]));

    float p[8];
    float sum = 0.f;
    if (act) {
#pragma unroll
        for (int e = 0; e < 8; ++e) {
            p[e] = (j0 + e <= rr) ? __expf(v[e] - m2) : 0.f;
            sum += p[e];
        }
    }
#pragma unroll
    for (int off = 32; off >= 1; off >>= 1) sum += __shfl_xor(sum, off);
    if (lane == 0) reds[wid] = sum;
    __syncthreads();
    float total = reds[0] + reds[1] + reds[2] + reds[3];
    float rinv = 1.0f / total;
    if (act) {
        bf16x8 o;
#pragma unroll
        for (int e = 0; e < 8; ++e) o[e] = (short)f2bf(p[e] * rinv);
        *(bf16x8*)(row + j0) = o;
    }
}

// ---------------- PV: O[b][m][n] = sum_k P[b][m][k] * Vt[b][n][k] ---------
__global__ __launch_bounds__(256) void gemm_pv(
    const ushort* __restrict__ Pb, const ushort* __restrict__ Vt,
    float* __restrict__ Out) {
    int bn = blockIdx.x, bm = blockIdx.y, b = blockIdx.z;
    __shared__ ushort sm[2 * 8192];
    f32x4 acc[4][4] = {};
    const ushort* Ag = Pb + (size_t)b * S_ * S_ + (size_t)bm * 128 * S_;
    const ushort* Bg = Vt + (size_t)b * D_ * S_ + (size_t)bn * 128 * S_;
    int nk = (bm + 1) * 4;               // causal K extent: (bm+1)*128 / 32
    mm_acc(Ag, S_, Bg, S_, nk, sm, acc);

    const int lane = threadIdx.x & 63;
    const int wid = threadIdx.x >> 6;
    const int wr = wid >> 1, wc = wid & 1;
    float* Crow = Out + (size_t)b * S_ * D_;
#pragma unroll
    for (int i = 0; i < 4; ++i)
#pragma unroll
        for (int j = 0; j < 4; ++j)
#pragma unroll
            for (int q = 0; q < 4; ++q) {
                int row = bm * 128 + wr * 64 + i * 16 + ((lane >> 4) << 2) + q;
                int col = bn * 128 + wc * 64 + j * 16 + (lane & 15);
                Crow[(size_t)row * D_ + col] = acc[i][j][q];
            }
}

extern "C" void kernel_launch(void* const* d_in, const int* in_sizes, int n_in,
                              void* d_out, int out_size, void* d_ws, size_t ws_size,
                              hipStream_t stream) {
    const float* x  = (const float*)d_in[0];
    const float* Wq = (const float*)d_in[1];
    const float* Wk = (const float*)d_in[2];
    const float* Wv = (const float*)d_in[3];
    float* out = (float*)d_out;

    char* ws = (char*)d_ws;
    ushort* xb = (ushort*)(ws);                          // 16 MB
    ushort* Wb = (ushort*)(ws + (16u << 20));            //  6 MB
    ushort* Qb = (ushort*)(ws + (22u << 20));            // 16 MB
    ushort* Kb = (ushort*)(ws + (38u << 20));            // 16 MB
    ushort* Vt = (ushort*)(ws + (54u << 20));            // 16 MB (transposed)
    ushort* Sb = (ushort*)(ws + (70u << 20));            // 32 MB (S then P)

    // 1) casts
    cast_f32_to_bf16<<<2048, 256, 0, stream>>>(x, xb, MTOT * D_ / 4);
    cast_f32_to_bf16<<<1024, 256, 0, stream>>>(Wq, Wb, D_ * D_ / 4);
    cast_f32_to_bf16<<<1024, 256, 0, stream>>>(Wk, Wb + (size_t)D_ * D_, D_ * D_ / 4);
    cast_f32_to_bf16<<<1024, 256, 0, stream>>>(Wv, Wb + (size_t)2 * D_ * D_, D_ * D_ / 4);

    // 2) QKV projection (z: 0=Q scaled, 1=K, 2=V^T)
    gemm_qkv<<<dim3(D_ / 128, MTOT / 128, 3), 256, 0, stream>>>(xb, Wb, Qb, Kb, Vt);

    // 3) scores (lower-triangular blocks only)
    gemm_scores<<<dim3(S_ / 128, S_ / 128, B_), 256, 0, stream>>>(Qb, Kb, Sb);

    // 4) causal softmax in place
    softmax_causal<<<MTOT, 256, 0, stream>>>(Sb);

    // 5) PV
    gemm_pv<<<dim3(D_ / 128, S_ / 128, B_), 256, 0, stream>>>(Sb, Vt, out);
}

// Round 3
// 260.210 us; speedup vs baseline: 1.0857x; 1.0857x over previous
//
#include <hip/hip_runtime.h>

typedef unsigned int uint;
typedef unsigned short ushort;
typedef __attribute__((ext_vector_type(8))) short bf16x8;
typedef __attribute__((ext_vector_type(4))) float f32x4;
typedef __attribute__((ext_vector_type(4))) float float4v;
typedef __attribute__((ext_vector_type(4))) ushort ushort4v;
typedef __attribute__((ext_vector_type(8))) ushort ushort8v;

#define B_ 4
#define S_ 2048
#define D_ 1024
#define MTOT (B_ * S_)   // 8192

__device__ __forceinline__ ushort f2bf(float f) {
    uint u = __builtin_bit_cast(uint, f);
    u = (u + 0x7FFFu + ((u >> 16) & 1u)) >> 16;   // RNE
    return (ushort)u;
}
__device__ __forceinline__ float bf2f(ushort h) {
    uint u = ((uint)h) << 16;
    return __builtin_bit_cast(float, u);
}

__device__ __forceinline__ void gload_lds16(const ushort* g, ushort* l) {
    __builtin_amdgcn_global_load_lds(
        (const __attribute__((address_space(1))) void*)g,
        (__attribute__((address_space(3))) void*)l, 16, 0, 0);
}

// ---------------- cast kernel: fp32 -> bf16, 4 elems/thread ----------------
__global__ void cast_f32_to_bf16(const float* __restrict__ src,
                                 ushort* __restrict__ dst, int n4) {
    int i = blockIdx.x * blockDim.x + threadIdx.x;
    int stride = gridDim.x * blockDim.x;
    for (; i < n4; i += stride) {
        float4v f = *(const float4v*)(src + (size_t)i * 4);
        ushort4v h;
        h.x = f2bf(f.x); h.y = f2bf(f.y); h.z = f2bf(f.z); h.w = f2bf(f.w);
        *(ushort4v*)(dst + (size_t)i * 4) = h;
    }
}

// ---------------- GEMM core: 128x128 tile, BK=32, 256 thr / 4 waves -------
// A tile [128][32] bf16 (K-contiguous), B tile [128][32] bf16 (K-contiguous).
// C = A * B^T.  LDS dest stays LINEAR for global_load_lds; the 16B column
// unit is XOR-swizzled on the GLOBAL SOURCE side and the same XOR is applied
// on the ds_read side (rule #21: both-sides-or-neither).
//   LDS[r][u] = G[r][u ^ f(r)],  f(r) = (r>>1)&3
// f(r)=(r>>1)&3 (NOT r&3): slot = (r&1, unit); within a 16-row quarter-wave
// each of the 8 slots must get exactly 2 rows -> need f to enumerate units
// 0..3 twice per parity class; (r>>1)&3 does, r&3 does not (4-way residual).
__device__ __forceinline__ void stage32(const ushort* __restrict__ Ag, int lda,
                                        const ushort* __restrict__ Bg, int ldb,
                                        int k0, ushort* smbuf, int t) {
#pragma unroll
    for (int i = 0; i < 2; ++i) {
        int U = i * 256 + t;                 // 16B-unit index within half-tile
        int r = U >> 2;                      // row 0..127
        int u = U & 3;                       // unit within row
        int c = ((u ^ ((r >> 1) & 3)) << 3); // swizzled source col (ushorts)
        int ldsbase = i * 2048 + (t & 192) * 8;  // wave-uniform (ushorts)
        gload_lds16(Ag + (size_t)r * lda + (k0 + c), smbuf + ldsbase);
        gload_lds16(Bg + (size_t)r * ldb + (k0 + c), smbuf + 4096 + ldsbase);
    }
}

__device__ __forceinline__ void mm_acc(const ushort* __restrict__ Ag, int lda,
                                       const ushort* __restrict__ Bg, int ldb,
                                       int nk, ushort* sm, f32x4 acc[4][4]) {
    const int t = threadIdx.x;
    const int lane = t & 63;
    const int wid = t >> 6;
    const int wr = wid >> 1, wc = wid & 1;
    const int ro = lane & 15;
    const int g = lane >> 4;                 // k-unit 0..3 (16B = 8 bf16)

    stage32(Ag, lda, Bg, ldb, 0, sm, t);
    __syncthreads();
    int cur = 0;
    for (int ks = 0; ks < nk; ++ks) {
        if (ks + 1 < nk)
            stage32(Ag, lda, Bg, ldb, (ks + 1) * 32, sm + (cur ^ 1) * 8192, t);
        const ushort* As = sm + cur * 8192;
        const ushort* Bs = As + 4096;
        // read swizzle: row = wr*64+i*16+ro ≡ ro (mod 16) so f(row)=(ro>>1)&3
        const int uo = ((g ^ ((ro >> 1) & 3)) << 3);
        bf16x8 af[4], bfr[4];
#pragma unroll
        for (int i = 0; i < 4; ++i)
            af[i] = *(const bf16x8*)(As + (wr * 64 + i * 16 + ro) * 32 + uo);
#pragma unroll
        for (int j = 0; j < 4; ++j)
            bfr[j] = *(const bf16x8*)(Bs + (wc * 64 + j * 16 + ro) * 32 + uo);
#pragma unroll
        for (int i = 0; i < 4; ++i)
#pragma unroll
            for (int j = 0; j < 4; ++j)
                acc[i][j] = __builtin_amdgcn_mfma_f32_16x16x32_bf16(
                    af[i], bfr[j], acc[i][j], 0, 0, 0);
        __syncthreads();
        cur ^= 1;
    }
}

// ---------------- QKV projection: C[m][n] = x[m][:] . W[n][:] -------------
// z=0 -> Q (scaled 1/32), z=1 -> K, z=2 -> V stored transposed per batch.
__global__ __launch_bounds__(256) void gemm_qkv(
    const ushort* __restrict__ xb, const ushort* __restrict__ Wb,
    ushort* __restrict__ Qb, ushort* __restrict__ Kb, ushort* __restrict__ Vt) {
    __shared__ ushort sm[2 * 8192];
    int bn = blockIdx.x, bm = blockIdx.y, z = blockIdx.z;
    f32x4 acc[4][4] = {};
    const ushort* Ag = xb + (size_t)bm * 128 * D_;
    const ushort* Bg = Wb + (size_t)z * D_ * D_ + (size_t)bn * 128 * D_;
    mm_acc(Ag, D_, Bg, D_, D_ / 32, sm, acc);

    const int t = threadIdx.x;
    const int lane = t & 63;
    const int wid = t >> 6;
    const int wr = wid >> 1, wc = wid & 1;
    const int ro = lane & 15;
    const int g = lane >> 4;

    if (z < 2) {
        const float scale = (z == 0) ? 0.03125f : 1.0f;
        ushort* Dst = (z == 0) ? Qb : Kb;
#pragma unroll
        for (int i = 0; i < 4; ++i)
#pragma unroll
            for (int j = 0; j < 4; ++j)
#pragma unroll
                for (int q = 0; q < 4; ++q) {
                    int row = wr * 64 + i * 16 + (g << 2) + q;
                    int col = bn * 128 + wc * 64 + j * 16 + ro;
                    int grow = bm * 128 + row;
                    Dst[(size_t)grow * D_ + col] = f2bf(acc[i][j][q] * scale);
                }
    } else {
        // V^T: bounce tile through LDS (reuse sm, swizzled) for coalesced
        // 16B stores. smT[col][row] layout: col stride 128 ushorts (256B);
        // row packed in 8B units, unit index ^= (col & 31).
        ushort* smT = sm;                    // 128*128 ushorts = 32KB exactly
#pragma unroll
        for (int i = 0; i < 4; ++i)
#pragma unroll
            for (int j = 0; j < 4; ++j) {
                int C = wc * 64 + j * 16 + ro;       // tile col (output row)
                int ru = wr * 16 + i * 4 + g;        // 4-row unit index 0..31
                ushort4v pk;
                pk.x = f2bf(acc[i][j][0]);
                pk.y = f2bf(acc[i][j][1]);
                pk.z = f2bf(acc[i][j][2]);
                pk.w = f2bf(acc[i][j][3]);
                *(ushort4v*)(smT + C * 128 + ((ru ^ (C & 31)) << 2)) = pk;
            }
        __syncthreads();
        int b = (bm * 128) >> 11;
        int s0 = (bm * 128) & 2047;
#pragma unroll
        for (int it = 0; it < 8; ++it) {
            int F = it * 256 + t;            // 16B-chunk index, 2048 total
            int o = F >> 4;                  // output row within tile 0..127
            int sc = F & 15;                 // 16B chunk along s
            ushort4v u0 = *(const ushort4v*)(smT + o * 128 + (((sc * 2) ^ (o & 31)) << 2));
            ushort4v u1 = *(const ushort4v*)(smT + o * 128 + (((sc * 2 + 1) ^ (o & 31)) << 2));
            ushort8v v8;
            v8[0] = u0.x; v8[1] = u0.y; v8[2] = u0.z; v8[3] = u0.w;
            v8[4] = u1.x; v8[5] = u1.y; v8[6] = u1.z; v8[7] = u1.w;
            *(ushort8v*)(Vt + (size_t)b * D_ * S_ +
                         (size_t)(bn * 128 + o) * S_ + s0 + sc * 8) = v8;
        }
    }
}

// ---------------- scores: S[b][m][n] = Q[b][m][:] . K[b][n][:] ------------
__global__ __launch_bounds__(256) void gemm_scores(
    const ushort* __restrict__ Qb, const ushort* __restrict__ Kb,
    ushort* __restrict__ Sb) {
    int bn = blockIdx.x, bm = blockIdx.y, b = blockIdx.z;
    if (bn > bm) return;                 // strictly-upper tiles never read
    __shared__ ushort sm[2 * 8192];
    f32x4 acc[4][4] = {};
    const ushort* Ag = Qb + (size_t)b * S_ * D_ + (size_t)bm * 128 * D_;
    const ushort* Bg = Kb + (size_t)b * S_ * D_ + (size_t)bn * 128 * D_;
    mm_acc(Ag, D_, Bg, D_, D_ / 32, sm, acc);

    const int lane = threadIdx.x & 63;
    const int wid = threadIdx.x >> 6;
    const int wr = wid >> 1, wc = wid & 1;
    const int ro = lane & 15;
    const int g = lane >> 4;
    ushort* Crow = Sb + (size_t)b * S_ * S_;
#pragma unroll
    for (int i = 0; i < 4; ++i)
#pragma unroll
        for (int j = 0; j < 4; ++j)
#pragma unroll
            for (int q = 0; q < 4; ++q) {
                int row = bm * 128 + wr * 64 + i * 16 + (g << 2) + q;
                int col = bn * 128 + wc * 64 + j * 16 + ro;
                Crow[(size_t)row * S_ + col] = f2bf(acc[i][j][q]);
            }
}

// ---------------- causal row softmax, in place, bf16, 1 wave/row ----------
__global__ __launch_bounds__(256) void softmax_causal(ushort* __restrict__ S) {
    int t = threadIdx.x;
    int lane = t & 63, w = t >> 6;
    int r = blockIdx.x * 4 + w;          // 0..8191
    int b = r >> 11, rr = r & 2047;
    int L = ((rr >> 7) + 1) << 7;        // padded causal length (mult of 128)
    ushort* row = S + (size_t)b * S_ * S_ + (size_t)rr * S_;

    float v[4][8];
    float mx = -1e30f;
#pragma unroll
    for (int c = 0; c < 4; ++c) {
        int j0 = c * 512 + lane * 8;
        if (j0 < L) {
            bf16x8 raw = *(const bf16x8*)(row + j0);
#pragma unroll
            for (int e = 0; e < 8; ++e) {
                float f = bf2f((ushort)raw[e]);
                v[c][e] = (j0 + e <= rr) ? f : -1e30f;
                mx = fmaxf(mx, v[c][e]);
            }
        }
    }
#pragma unroll
    for (int off = 32; off >= 1; off >>= 1) mx = fmaxf(mx, __shfl_xor(mx, off));

    float sum = 0.f;
#pragma unroll
    for (int c = 0; c < 4; ++c) {
        int j0 = c * 512 + lane * 8;
        if (j0 < L) {
#pragma unroll
            for (int e = 0; e < 8; ++e) {
                v[c][e] = (j0 + e <= rr) ? __expf(v[c][e] - mx) : 0.f;
                sum += v[c][e];
            }
        }
    }
#pragma unroll
    for (int off = 32; off >= 1; off >>= 1) sum += __shfl_xor(sum, off);
    float rinv = 1.0f / sum;

#pragma unroll
    for (int c = 0; c < 4; ++c) {
        int j0 = c * 512 + lane * 8;
        if (j0 < L) {
            bf16x8 o;
#pragma unroll
            for (int e = 0; e < 8; ++e) o[e] = (short)f2bf(v[c][e] * rinv);
            *(bf16x8*)(row + j0) = o;
        }
    }
}

// ---------------- PV: O[b][m][n] = sum_k P[b][m][k] * Vt[b][n][k] ---------
__global__ __launch_bounds__(256) void gemm_pv(
    const ushort* __restrict__ Pb, const ushort* __restrict__ Vt,
    float* __restrict__ Out) {
    int bn = blockIdx.x, bm = blockIdx.y, b = blockIdx.z;
    __shared__ ushort sm[2 * 8192];
    f32x4 acc[4][4] = {};
    const ushort* Ag = Pb + (size_t)b * S_ * S_ + (size_t)bm * 128 * S_;
    const ushort* Bg = Vt + (size_t)b * D_ * S_ + (size_t)bn * 128 * S_;
    int nk = (bm + 1) * 4;               // causal K extent: (bm+1)*128 / 32
    mm_acc(Ag, S_, Bg, S_, nk, sm, acc);

    const int lane = threadIdx.x & 63;
    const int wid = threadIdx.x >> 6;
    const int wr = wid >> 1, wc = wid & 1;
    const int ro = lane & 15;
    const int g = lane >> 4;
    float* Crow = Out + (size_t)b * S_ * D_;
#pragma unroll
    for (int i = 0; i < 4; ++i)
#pragma unroll
        for (int j = 0; j < 4; ++j)
#pragma unroll
            for (int q = 0; q < 4; ++q) {
                int row = bm * 128 + wr * 64 + i * 16 + (g << 2) + q;
                int col = bn * 128 + wc * 64 + j * 16 + ro;
                Crow[(size_t)row * D_ + col] = acc[i][j][q];
            }
}

extern "C" void kernel_launch(void* const* d_in, const int* in_sizes, int n_in,
                              void* d_out, int out_size, void* d_ws, size_t ws_size,
                              hipStream_t stream) {
    const float* x  = (const float*)d_in[0];
    const float* Wq = (const float*)d_in[1];
    const float* Wk = (const float*)d_in[2];
    const float* Wv = (const float*)d_in[3];
    float* out = (float*)d_out;

    char* ws = (char*)d_ws;
    ushort* xb = (ushort*)(ws);                          // 16 MB
    ushort* Wb = (ushort*)(ws + (16u << 20));            //  6 MB
    ushort* Qb = (ushort*)(ws + (22u << 20));            // 16 MB
    ushort* Kb = (ushort*)(ws + (38u << 20));            // 16 MB
    ushort* Vt = (ushort*)(ws + (54u << 20));            // 16 MB (transposed)
    ushort* Sb = (ushort*)(ws + (70u << 20));            // 32 MB (S then P)

    // 1) casts
    cast_f32_to_bf16<<<2048, 256, 0, stream>>>(x, xb, MTOT * D_ / 4);
    cast_f32_to_bf16<<<1024, 256, 0, stream>>>(Wq, Wb, D_ * D_ / 4);
    cast_f32_to_bf16<<<1024, 256, 0, stream>>>(Wk, Wb + (size_t)D_ * D_, D_ * D_ / 4);
    cast_f32_to_bf16<<<1024, 256, 0, stream>>>(Wv, Wb + (size_t)2 * D_ * D_, D_ * D_ / 4);

    // 2) QKV projection (z: 0=Q scaled, 1=K, 2=V^T)
    gemm_qkv<<<dim3(D_ / 128, MTOT / 128, 3), 256, 0, stream>>>(xb, Wb, Qb, Kb, Vt);

    // 3) scores (lower-triangular blocks only)
    gemm_scores<<<dim3(S_ / 128, S_ / 128, B_), 256, 0, stream>>>(Qb, Kb, Sb);

    // 4) causal softmax in place (1 wave per row)
    softmax_causal<<<MTOT / 4, 256, 0, stream>>>(Sb);

    // 5) PV
    gemm_pv<<<dim3(D_ / 128, S_ / 128, B_), 256, 0, stream>>>(Sb, Vt, out);
}

// Round 4
// 254.321 us; speedup vs baseline: 1.1108x; 1.0232x over previous
//
#include <hip/hip_runtime.h>

typedef unsigned int uint;
typedef unsigned short ushort;
typedef __attribute__((ext_vector_type(8))) short bf16x8;
typedef __attribute__((ext_vector_type(4))) float f32x4;
typedef __attribute__((ext_vector_type(4))) float float4v;
typedef __attribute__((ext_vector_type(4))) ushort ushort4v;
typedef __attribute__((ext_vector_type(8))) ushort ushort8v;

#define B_ 4
#define S_ 2048
#define D_ 1024
#define MTOT (B_ * S_)   // 8192

__device__ __forceinline__ ushort f2bf(float f) {
    uint u = __builtin_bit_cast(uint, f);
    u = (u + 0x7FFFu + ((u >> 16) & 1u)) >> 16;   // RNE
    return (ushort)u;
}
__device__ __forceinline__ float bf2f(ushort h) {
    uint u = ((uint)h) << 16;
    return __builtin_bit_cast(float, u);
}

__device__ __forceinline__ void gload_lds16(const ushort* g, ushort* l) {
    __builtin_amdgcn_global_load_lds(
        (const __attribute__((address_space(1))) void*)g,
        (__attribute__((address_space(3))) void*)l, 16, 0, 0);
}

// ---------------- fused cast: x (8M) + Wq/Wk/Wv (1M each) -> bf16 ----------
#define XU (MTOT * D_ / 4)        // 2097152 float4 units for x
#define WU (D_ * D_ / 4)          // 262144 per W
__global__ void cast_all(const float* __restrict__ x,
                         const float* __restrict__ wq,
                         const float* __restrict__ wk,
                         const float* __restrict__ wv,
                         ushort* __restrict__ xb, ushort* __restrict__ wb) {
    int i = blockIdx.x * blockDim.x + threadIdx.x;
    int stride = gridDim.x * blockDim.x;
    for (; i < XU + 3 * WU; i += stride) {
        const float* src;
        ushort* dst;
        if (i < XU) { src = x + (size_t)i * 4; dst = xb + (size_t)i * 4; }
        else {
            int j = i - XU;
            int z = j / WU, o = j % WU;
            const float* w = (z == 0) ? wq : (z == 1) ? wk : wv;
            src = w + (size_t)o * 4;
            dst = wb + (size_t)z * D_ * D_ + (size_t)o * 4;
        }
        float4v f = *(const float4v*)src;
        ushort4v h;
        h.x = f2bf(f.x); h.y = f2bf(f.y); h.z = f2bf(f.z); h.w = f2bf(f.w);
        *(ushort4v*)dst = h;
    }
}

// ---------------- GEMM core: 128x128 tile, BK=32, 256 thr / 4 waves -------
// 4-slot LDS ring (16KB/slot), staged 3 K-tiles ahead, counted vmcnt —
// loads stay in flight ACROSS barriers (T3/T4 essence; never vmcnt(0) in
// steady state).  Swizzle: LDS[r][u] = G[r][u ^ ((r>>1)&3)] on both the
// global source and the ds_read side (rule #21), conflict-free (R2: 6.3M->0).
__device__ __forceinline__ void stage_tile(const ushort* __restrict__ Ag, int lda,
                                           const ushort* __restrict__ Bg, int ldb,
                                           int k0, ushort* slot, int t) {
#pragma unroll
    for (int i = 0; i < 2; ++i) {
        int U = i * 256 + t;                 // 16B-unit index within 8KB half
        int r = U >> 2;                      // row 0..127
        int u = U & 3;                       // unit within row
        int c = ((u ^ ((r >> 1) & 3)) << 3); // swizzled source col (ushorts)
        int ldsbase = i * 2048 + (t & 192) * 8;  // wave-uniform (ushorts)
        gload_lds16(Ag + (size_t)r * lda + (k0 + c), slot + ldsbase);
        gload_lds16(Bg + (size_t)r * ldb + (k0 + c), slot + 4096 + ldsbase);
    }
}

// Per wave per tile: 4 gload_lds instrs -> vmcnt thresholds 12/8/4/0.
__device__ __forceinline__ void mm_pipe(const ushort* __restrict__ Ag, int lda,
                                        const ushort* __restrict__ Bg, int ldb,
                                        int nk, ushort* sm, f32x4 acc[4][4]) {
    const int t = threadIdx.x;
    const int lane = t & 63;
    const int wid = t >> 6;
    const int wr = wid >> 1, wc = wid & 1;
    const int ro = lane & 15;
    const int g = lane >> 4;                 // k-unit 0..3 (16B = 8 bf16)
    const int uo = ((g ^ ((ro >> 1) & 3)) << 3);  // swizzled read unit

#pragma unroll
    for (int p = 0; p < 3; ++p)
        if (p < nk) stage_tile(Ag, lda, Bg, ldb, p * 32, sm + p * 8192, t);

    for (int ks = 0; ks < nk; ++ks) {
        // WAR-safe: slot (ks+3)&3 == (ks-1)&3 was last read before iter
        // ks-1's end barrier (program order + barrier separate read/write).
        if (ks + 3 < nk)
            stage_tile(Ag, lda, Bg, ldb, (ks + 3) * 32,
                       sm + ((ks + 3) & 3) * 8192, t);
        int ahead = nk - 1 - ks;             // tiles still in flight after ks
        if (ahead >= 3)      asm volatile("s_waitcnt vmcnt(12)" ::: "memory");
        else if (ahead == 2) asm volatile("s_waitcnt vmcnt(8)"  ::: "memory");
        else if (ahead == 1) asm volatile("s_waitcnt vmcnt(4)"  ::: "memory");
        else                 asm volatile("s_waitcnt vmcnt(0)"  ::: "memory");
        __builtin_amdgcn_s_barrier();        // publish tile ks to all waves
        asm volatile("" ::: "memory");

        const ushort* As = sm + (ks & 3) * 8192;
        const ushort* Bs = As + 4096;
        bf16x8 af[4], bfr[4];
#pragma unroll
        for (int i = 0; i < 4; ++i)
            af[i] = *(const bf16x8*)(As + (wr * 64 + i * 16 + ro) * 32 + uo);
#pragma unroll
        for (int j = 0; j < 4; ++j)
            bfr[j] = *(const bf16x8*)(Bs + (wc * 64 + j * 16 + ro) * 32 + uo);
        __builtin_amdgcn_s_setprio(1);
#pragma unroll
        for (int i = 0; i < 4; ++i)
#pragma unroll
            for (int j = 0; j < 4; ++j)
                acc[i][j] = __builtin_amdgcn_mfma_f32_16x16x32_bf16(
                    af[i], bfr[j], acc[i][j], 0, 0, 0);
        __builtin_amdgcn_s_setprio(0);
        asm volatile("" ::: "memory");
        __builtin_amdgcn_s_barrier();        // readers done -> slot reusable
    }
}

// ---------------- QKV projection: C[m][n] = x[m][:] . W[n][:] -------------
// z=0 -> Q (scaled 1/32), z=1 -> K, z=2 -> V stored transposed per batch.
__global__ __launch_bounds__(256) void gemm_qkv(
    const ushort* __restrict__ xb, const ushort* __restrict__ Wb,
    ushort* __restrict__ Qb, ushort* __restrict__ Kb, ushort* __restrict__ Vt) {
    __shared__ ushort sm[4 * 8192];
    int bn = blockIdx.x, bm = blockIdx.y, z = blockIdx.z;
    f32x4 acc[4][4] = {};
    const ushort* Ag = xb + (size_t)bm * 128 * D_;
    const ushort* Bg = Wb + (size_t)z * D_ * D_ + (size_t)bn * 128 * D_;
    mm_pipe(Ag, D_, Bg, D_, D_ / 32, sm, acc);

    const int t = threadIdx.x;
    const int lane = t & 63;
    const int wid = t >> 6;
    const int wr = wid >> 1, wc = wid & 1;
    const int ro = lane & 15;
    const int g = lane >> 4;

    if (z < 2) {
        const float scale = (z == 0) ? 0.03125f : 1.0f;
        ushort* Dst = (z == 0) ? Qb : Kb;
#pragma unroll
        for (int i = 0; i < 4; ++i)
#pragma unroll
            for (int j = 0; j < 4; ++j)
#pragma unroll
                for (int q = 0; q < 4; ++q) {
                    int row = wr * 64 + i * 16 + (g << 2) + q;
                    int col = bn * 128 + wc * 64 + j * 16 + ro;
                    int grow = bm * 128 + row;
                    Dst[(size_t)grow * D_ + col] = f2bf(acc[i][j][q] * scale);
                }
    } else {
        // V^T: bounce tile through LDS (reuse sm, swizzled) for coalesced
        // 16B stores. smT[col][row]: col stride 128 ushorts; 8B row-units,
        // unit index ^= (col & 31).
        ushort* smT = sm;                    // 128*128 ushorts = 32KB
        __syncthreads();                     // ring fully consumed; reuse
#pragma unroll
        for (int i = 0; i < 4; ++i)
#pragma unroll
            for (int j = 0; j < 4; ++j) {
                int C = wc * 64 + j * 16 + ro;       // tile col (output row)
                int ru = wr * 16 + i * 4 + g;        // 4-row unit index 0..31
                ushort4v pk;
                pk.x = f2bf(acc[i][j][0]);
                pk.y = f2bf(acc[i][j][1]);
                pk.z = f2bf(acc[i][j][2]);
                pk.w = f2bf(acc[i][j][3]);
                *(ushort4v*)(smT + C * 128 + ((ru ^ (C & 31)) << 2)) = pk;
            }
        __syncthreads();
        int b = (bm * 128) >> 11;
        int s0 = (bm * 128) & 2047;
#pragma unroll
        for (int it = 0; it < 8; ++it) {
            int F = it * 256 + t;            // 16B-chunk index, 2048 total
            int o = F >> 4;                  // output row within tile 0..127
            int sc = F & 15;                 // 16B chunk along s
            ushort4v u0 = *(const ushort4v*)(smT + o * 128 + (((sc * 2) ^ (o & 31)) << 2));
            ushort4v u1 = *(const ushort4v*)(smT + o * 128 + (((sc * 2 + 1) ^ (o & 31)) << 2));
            ushort8v v8;
            v8[0] = u0.x; v8[1] = u0.y; v8[2] = u0.z; v8[3] = u0.w;
            v8[4] = u1.x; v8[5] = u1.y; v8[6] = u1.z; v8[7] = u1.w;
            *(ushort8v*)(Vt + (size_t)b * D_ * S_ +
                         (size_t)(bn * 128 + o) * S_ + s0 + sc * 8) = v8;
        }
    }
}

// ---------------- scores: S[b][m][n] = Q[b][m][:] . K[b][n][:] ------------
__global__ __launch_bounds__(256) void gemm_scores(
    const ushort* __restrict__ Qb, const ushort* __restrict__ Kb,
    ushort* __restrict__ Sb) {
    int bn = blockIdx.x, bm = blockIdx.y, b = blockIdx.z;
    if (bn > bm) return;                 // strictly-upper tiles never read
    __shared__ ushort sm[4 * 8192];
    f32x4 acc[4][4] = {};
    const ushort* Ag = Qb + (size_t)b * S_ * D_ + (size_t)bm * 128 * D_;
    const ushort* Bg = Kb + (size_t)b * S_ * D_ + (size_t)bn * 128 * D_;
    mm_pipe(Ag, D_, Bg, D_, D_ / 32, sm, acc);

    const int lane = threadIdx.x & 63;
    const int wid = threadIdx.x >> 6;
    const int wr = wid >> 1, wc = wid & 1;
    const int ro = lane & 15;
    const int g = lane >> 4;
    ushort* Crow = Sb + (size_t)b * S_ * S_;
#pragma unroll
    for (int i = 0; i < 4; ++i)
#pragma unroll
        for (int j = 0; j < 4; ++j)
#pragma unroll
            for (int q = 0; q < 4; ++q) {
                int row = bm * 128 + wr * 64 + i * 16 + (g << 2) + q;
                int col = bn * 128 + wc * 64 + j * 16 + ro;
                Crow[(size_t)row * S_ + col] = f2bf(acc[i][j][q]);
            }
}

// ---------------- causal row softmax, in place, bf16, 1 wave/row ----------
__global__ __launch_bounds__(256) void softmax_causal(ushort* __restrict__ S) {
    int t = threadIdx.x;
    int lane = t & 63, w = t >> 6;
    int r = blockIdx.x * 4 + w;          // 0..8191
    int b = r >> 11, rr = r & 2047;
    int L = ((rr >> 7) + 1) << 7;        // padded causal length (mult of 128)
    ushort* row = S + (size_t)b * S_ * S_ + (size_t)rr * S_;

    float v[4][8];
    float mx = -1e30f;
#pragma unroll
    for (int c = 0; c < 4; ++c) {
        int j0 = c * 512 + lane * 8;
        if (j0 < L) {
            bf16x8 raw = *(const bf16x8*)(row + j0);
#pragma unroll
            for (int e = 0; e < 8; ++e) {
                float f = bf2f((ushort)raw[e]);
                v[c][e] = (j0 + e <= rr) ? f : -1e30f;
                mx = fmaxf(mx, v[c][e]);
            }
        }
    }
#pragma unroll
    for (int off = 32; off >= 1; off >>= 1) mx = fmaxf(mx, __shfl_xor(mx, off));

    float sum = 0.f;
#pragma unroll
    for (int c = 0; c < 4; ++c) {
        int j0 = c * 512 + lane * 8;
        if (j0 < L) {
#pragma unroll
            for (int e = 0; e < 8; ++e) {
                v[c][e] = (j0 + e <= rr) ? __expf(v[c][e] - mx) : 0.f;
                sum += v[c][e];
            }
        }
    }
#pragma unroll
    for (int off = 32; off >= 1; off >>= 1) sum += __shfl_xor(sum, off);
    float rinv = 1.0f / sum;

#pragma unroll
    for (int c = 0; c < 4; ++c) {
        int j0 = c * 512 + lane * 8;
        if (j0 < L) {
            bf16x8 o;
#pragma unroll
            for (int e = 0; e < 8; ++e) o[e] = (short)f2bf(v[c][e] * rinv);
            *(bf16x8*)(row + j0) = o;
        }
    }
}

// ---------------- PV: O[b][m][n] = sum_k P[b][m][k] * Vt[b][n][k] ---------
// Longest-first: bm reversed so K=2048 blocks dispatch before K=128 ones.
__global__ __launch_bounds__(256) void gemm_pv(
    const ushort* __restrict__ Pb, const ushort* __restrict__ Vt,
    float* __restrict__ Out) {
    int bn = blockIdx.x, b = blockIdx.z;
    int bm = (S_ / 128 - 1) - blockIdx.y;    // 15..0: heavy tiles first
    __shared__ ushort sm[4 * 8192];
    f32x4 acc[4][4] = {};
    const ushort* Ag = Pb + (size_t)b * S_ * S_ + (size_t)bm * 128 * S_;
    const ushort* Bg = Vt + (size_t)b * D_ * S_ + (size_t)bn * 128 * S_;
    int nk = (bm + 1) * 4;               // causal K extent: (bm+1)*128 / 32
    mm_pipe(Ag, S_, Bg, S_, nk, sm, acc);

    const int lane = threadIdx.x & 63;
    const int wid = threadIdx.x >> 6;
    const int wr = wid >> 1, wc = wid & 1;
    const int ro = lane & 15;
    const int g = lane >> 4;
    float* Crow = Out + (size_t)b * S_ * D_;
#pragma unroll
    for (int i = 0; i < 4; ++i)
#pragma unroll
        for (int j = 0; j < 4; ++j)
#pragma unroll
            for (int q = 0; q < 4; ++q) {
                int row = bm * 128 + wr * 64 + i * 16 + (g << 2) + q;
                int col = bn * 128 + wc * 64 + j * 16 + ro;
                Crow[(size_t)row * D_ + col] = acc[i][j][q];
            }
}

extern "C" void kernel_launch(void* const* d_in, const int* in_sizes, int n_in,
                              void* d_out, int out_size, void* d_ws, size_t ws_size,
                              hipStream_t stream) {
    const float* x  = (const float*)d_in[0];
    const float* Wq = (const float*)d_in[1];
    const float* Wk = (const float*)d_in[2];
    const float* Wv = (const float*)d_in[3];
    float* out = (float*)d_out;

    char* ws = (char*)d_ws;
    ushort* xb = (ushort*)(ws);                          // 16 MB
    ushort* Wb = (ushort*)(ws + (16u << 20));            //  6 MB
    ushort* Qb = (ushort*)(ws + (22u << 20));            // 16 MB
    ushort* Kb = (ushort*)(ws + (38u << 20));            // 16 MB
    ushort* Vt = (ushort*)(ws + (54u << 20));            // 16 MB (transposed)
    ushort* Sb = (ushort*)(ws + (70u << 20));            // 32 MB (S then P)

    // 1) single fused cast
    cast_all<<<2048, 256, 0, stream>>>(x, Wq, Wk, Wv, xb, Wb);

    // 2) QKV projection (z: 0=Q scaled, 1=K, 2=V^T)
    gemm_qkv<<<dim3(D_ / 128, MTOT / 128, 3), 256, 0, stream>>>(xb, Wb, Qb, Kb, Vt);

    // 3) scores (lower-triangular blocks only)
    gemm_scores<<<dim3(S_ / 128, S_ / 128, B_), 256, 0, stream>>>(Qb, Kb, Sb);

    // 4) causal softmax in place (1 wave per row)
    softmax_causal<<<MTOT / 4, 256, 0, stream>>>(Sb);

    // 5) PV (longest-first)
    gemm_pv<<<dim3(D_ / 128, S_ / 128, B_), 256, 0, stream>>>(Sb, Vt, out);
}

// Round 5
// 223.032 us; speedup vs baseline: 1.2666x; 1.1403x over previous
//
#include <hip/hip_runtime.h>

typedef unsigned int uint;
typedef unsigned short ushort;
typedef __attribute__((ext_vector_type(8))) short bf16x8;
typedef __attribute__((ext_vector_type(4))) float f32x4;
typedef __attribute__((ext_vector_type(4))) float float4v;
typedef __attribute__((ext_vector_type(4))) ushort ushort4v;
typedef __attribute__((ext_vector_type(8))) ushort ushort8v;

#define B_ 4
#define S_ 2048
#define D_ 1024
#define MTOT (B_ * S_)   // 8192

__device__ __forceinline__ ushort f2bf(float f) {
    uint u = __builtin_bit_cast(uint, f);
    u = (u + 0x7FFFu + ((u >> 16) & 1u)) >> 16;   // RNE
    return (ushort)u;
}
__device__ __forceinline__ float bf2f(ushort h) {
    uint u = ((uint)h) << 16;
    return __builtin_bit_cast(float, u);
}

__device__ __forceinline__ void gload_lds16(const ushort* g, ushort* l) {
    __builtin_amdgcn_global_load_lds(
        (const __attribute__((address_space(1))) void*)g,
        (__attribute__((address_space(3))) void*)l, 16, 0, 0);
}

// T1 bijective XCD swizzle: hw bid (round-robin over 8 XCDs) -> logical id
// such that each XCD owns a contiguous logical chunk. Requires nwg % 8 == 0.
__device__ __forceinline__ int xcd_swz(int bid, int nwg) {
    int cpx = nwg >> 3;
    return (bid & 7) * cpx + (bid >> 3);
}

// ---------------- fused cast: x (8M) + Wq/Wk/Wv (1M each) -> bf16 ----------
#define XU (MTOT * D_ / 4)        // 2097152 float4 units for x
#define WU (D_ * D_ / 4)          // 262144 per W
__global__ void cast_all(const float* __restrict__ x,
                         const float* __restrict__ wq,
                         const float* __restrict__ wk,
                         const float* __restrict__ wv,
                         ushort* __restrict__ xb, ushort* __restrict__ wb) {
    int i = blockIdx.x * blockDim.x + threadIdx.x;
    int stride = gridDim.x * blockDim.x;
    for (; i < XU + 3 * WU; i += stride) {
        const float* src;
        ushort* dst;
        if (i < XU) { src = x + (size_t)i * 4; dst = xb + (size_t)i * 4; }
        else {
            int j = i - XU;
            int z = j / WU, o = j % WU;
            const float* w = (z == 0) ? wq : (z == 1) ? wk : wv;
            src = w + (size_t)o * 4;
            dst = wb + (size_t)z * D_ * D_ + (size_t)o * 4;
        }
        float4v f = *(const float4v*)src;
        ushort4v h;
        h.x = f2bf(f.x); h.y = f2bf(f.y); h.z = f2bf(f.z); h.w = f2bf(f.w);
        *(ushort4v*)dst = h;
    }
}

// ---------------- GEMM core: 128x128 tile, BK=32, 256 thr / 4 waves -------
// 3-slot LDS ring (16KB/slot = 48KB -> 3 blocks/CU), staged 2 K-tiles ahead,
// counted vmcnt (8/4/0; 4 gload_lds per wave per tile). Swizzle: LDS[r][u] =
// G[r][u ^ ((r>>1)&3)] on both global source and ds_read (rule #21),
// conflict-free (R2: 6.3M -> 0).
__device__ __forceinline__ void stage_tile(const ushort* __restrict__ Ag, int lda,
                                           const ushort* __restrict__ Bg, int ldb,
                                           int k0, ushort* slot, int t) {
#pragma unroll
    for (int i = 0; i < 2; ++i) {
        int U = i * 256 + t;                 // 16B-unit index within 8KB half
        int r = U >> 2;                      // row 0..127
        int u = U & 3;                       // unit within row
        int c = ((u ^ ((r >> 1) & 3)) << 3); // swizzled source col (ushorts)
        int ldsbase = i * 2048 + (t & 192) * 8;  // wave-uniform (ushorts)
        gload_lds16(Ag + (size_t)r * lda + (k0 + c), slot + ldsbase);
        gload_lds16(Bg + (size_t)r * ldb + (k0 + c), slot + 4096 + ldsbase);
    }
}

__device__ __forceinline__ void mm_pipe(const ushort* __restrict__ Ag, int lda,
                                        const ushort* __restrict__ Bg, int ldb,
                                        int nk, ushort* sm, f32x4 acc[4][4]) {
    const int t = threadIdx.x;
    const int lane = t & 63;
    const int wid = t >> 6;
    const int wr = wid >> 1, wc = wid & 1;
    const int ro = lane & 15;
    const int g = lane >> 4;                 // k-unit 0..3 (16B = 8 bf16)
    const int uo = ((g ^ ((ro >> 1) & 3)) << 3);  // swizzled read unit

#pragma unroll
    for (int p = 0; p < 2; ++p)
        if (p < nk) stage_tile(Ag, lda, Bg, ldb, p * 32, sm + p * 8192, t);

    int slot_n = 2 % 3;                      // slot for tile ks+2
    int slot_c = 0;                          // slot for tile ks
    for (int ks = 0; ks < nk; ++ks) {
        // WAR-safe: slot (ks+2)%3 == (ks-1)%3, whose ds_reads were consumed
        // into registers before iter ks-1's end barrier.
        if (ks + 2 < nk)
            stage_tile(Ag, lda, Bg, ldb, (ks + 2) * 32, sm + slot_n * 8192, t);
        int ahead = nk - 1 - ks;             // tiles still in flight after ks
        if (ahead >= 2)      asm volatile("s_waitcnt vmcnt(8)" ::: "memory");
        else if (ahead == 1) asm volatile("s_waitcnt vmcnt(4)" ::: "memory");
        else                 asm volatile("s_waitcnt vmcnt(0)" ::: "memory");
        __builtin_amdgcn_s_barrier();        // publish tile ks to all waves
        asm volatile("" ::: "memory");

        const ushort* As = sm + slot_c * 8192;
        const ushort* Bs = As + 4096;
        bf16x8 af[4], bfr[4];
#pragma unroll
        for (int i = 0; i < 4; ++i)
            af[i] = *(const bf16x8*)(As + (wr * 64 + i * 16 + ro) * 32 + uo);
#pragma unroll
        for (int j = 0; j < 4; ++j)
            bfr[j] = *(const bf16x8*)(Bs + (wc * 64 + j * 16 + ro) * 32 + uo);
        __builtin_amdgcn_s_setprio(1);
#pragma unroll
        for (int i = 0; i < 4; ++i)
#pragma unroll
            for (int j = 0; j < 4; ++j)
                acc[i][j] = __builtin_amdgcn_mfma_f32_16x16x32_bf16(
                    af[i], bfr[j], acc[i][j], 0, 0, 0);
        __builtin_amdgcn_s_setprio(0);
        asm volatile("" ::: "memory");
        __builtin_amdgcn_s_barrier();        // readers done -> slot reusable
        slot_c = (slot_c == 2) ? 0 : slot_c + 1;
        slot_n = (slot_n == 2) ? 0 : slot_n + 1;
    }
}

// ---------------- QKV projection: C[m][n] = x[m][:] . W[n][:] -------------
// Logical order: z major, then bm, then bn (bn fastest) -> one XCD chunk =
// one W-set (2MB, L2-resident) x 24 A-panels each reused 8x back-to-back.
__global__ __launch_bounds__(256) void gemm_qkv(
    const ushort* __restrict__ xb, const ushort* __restrict__ Wb,
    ushort* __restrict__ Qb, ushort* __restrict__ Kb, ushort* __restrict__ Vt) {
    __shared__ ushort sm[3 * 8192];
    int l = xcd_swz(blockIdx.x, 3 * 64 * 8);
    int bn = l & 7;
    int bm = (l >> 3) & 63;
    int z  = l >> 9;
    f32x4 acc[4][4] = {};
    const ushort* Ag = xb + (size_t)bm * 128 * D_;
    const ushort* Bg = Wb + (size_t)z * D_ * D_ + (size_t)bn * 128 * D_;
    mm_pipe(Ag, D_, Bg, D_, D_ / 32, sm, acc);

    const int t = threadIdx.x;
    const int lane = t & 63;
    const int wid = t >> 6;
    const int wr = wid >> 1, wc = wid & 1;
    const int ro = lane & 15;
    const int g = lane >> 4;

    if (z < 2) {
        const float scale = (z == 0) ? 0.03125f : 1.0f;
        ushort* Dst = (z == 0) ? Qb : Kb;
#pragma unroll
        for (int i = 0; i < 4; ++i)
#pragma unroll
            for (int j = 0; j < 4; ++j)
#pragma unroll
                for (int q = 0; q < 4; ++q) {
                    int row = wr * 64 + i * 16 + (g << 2) + q;
                    int col = bn * 128 + wc * 64 + j * 16 + ro;
                    int grow = bm * 128 + row;
                    Dst[(size_t)grow * D_ + col] = f2bf(acc[i][j][q] * scale);
                }
    } else {
        // V^T: bounce tile through LDS (reuse ring slot 0+1, swizzled) for
        // coalesced 16B stores. smT[col][row]: col stride 128 ushorts; 8B
        // row-units, unit index ^= (col & 31).
        ushort* smT = sm;                    // 128*128 ushorts = 32KB
        __syncthreads();                     // ring fully consumed; reuse
#pragma unroll
        for (int i = 0; i < 4; ++i)
#pragma unroll
            for (int j = 0; j < 4; ++j) {
                int C = wc * 64 + j * 16 + ro;       // tile col (output row)
                int ru = wr * 16 + i * 4 + g;        // 4-row unit index 0..31
                ushort4v pk;
                pk.x = f2bf(acc[i][j][0]);
                pk.y = f2bf(acc[i][j][1]);
                pk.z = f2bf(acc[i][j][2]);
                pk.w = f2bf(acc[i][j][3]);
                *(ushort4v*)(smT + C * 128 + ((ru ^ (C & 31)) << 2)) = pk;
            }
        __syncthreads();
        int b = (bm * 128) >> 11;
        int s0 = (bm * 128) & 2047;
#pragma unroll
        for (int it = 0; it < 8; ++it) {
            int F = it * 256 + t;            // 16B-chunk index, 2048 total
            int o = F >> 4;                  // output row within tile 0..127
            int sc = F & 15;                 // 16B chunk along s
            ushort4v u0 = *(const ushort4v*)(smT + o * 128 + (((sc * 2) ^ (o & 31)) << 2));
            ushort4v u1 = *(const ushort4v*)(smT + o * 128 + (((sc * 2 + 1) ^ (o & 31)) << 2));
            ushort8v v8;
            v8[0] = u0.x; v8[1] = u0.y; v8[2] = u0.z; v8[3] = u0.w;
            v8[4] = u1.x; v8[5] = u1.y; v8[6] = u1.z; v8[7] = u1.w;
            *(ushort8v*)(Vt + (size_t)b * D_ * S_ +
                         (size_t)(bn * 128 + o) * S_ + s0 + sc * 8) = v8;
        }
    }
}

// ---------------- scores: S[b][m][n] = Q[b][m][:] . K[b][n][:] ------------
// Compact lower-triangular enumeration (no dead blocks): 136 (bm,bn) pairs
// per batch, bn fastest within bm (shares Q-panel). nwg = 544, %8 == 0.
__global__ __launch_bounds__(256) void gemm_scores(
    const ushort* __restrict__ Qb, const ushort* __restrict__ Kb,
    ushort* __restrict__ Sb) {
    int l = xcd_swz(blockIdx.x, 4 * 136);
    int b = l / 136;
    int tt = l - b * 136;
    int bm = 0;
    while (((bm + 1) * (bm + 2)) / 2 <= tt) ++bm;   // <= 15 iterations
    int bn = tt - (bm * (bm + 1)) / 2;
    __shared__ ushort sm[3 * 8192];
    f32x4 acc[4][4] = {};
    const ushort* Ag = Qb + (size_t)b * S_ * D_ + (size_t)bm * 128 * D_;
    const ushort* Bg = Kb + (size_t)b * S_ * D_ + (size_t)bn * 128 * D_;
    mm_pipe(Ag, D_, Bg, D_, D_ / 32, sm, acc);

    const int lane = threadIdx.x & 63;
    const int wid = threadIdx.x >> 6;
    const int wr = wid >> 1, wc = wid & 1;
    const int ro = lane & 15;
    const int g = lane >> 4;
    ushort* Crow = Sb + (size_t)b * S_ * S_;
#pragma unroll
    for (int i = 0; i < 4; ++i)
#pragma unroll
        for (int j = 0; j < 4; ++j)
#pragma unroll
            for (int q = 0; q < 4; ++q) {
                int row = bm * 128 + wr * 64 + i * 16 + (g << 2) + q;
                int col = bn * 128 + wc * 64 + j * 16 + ro;
                Crow[(size_t)row * S_ + col] = f2bf(acc[i][j][q]);
            }
}

// ---------------- causal row softmax, in place, bf16, 1 wave/row ----------
__global__ __launch_bounds__(256) void softmax_causal(ushort* __restrict__ S) {
    int t = threadIdx.x;
    int lane = t & 63, w = t >> 6;
    int r = blockIdx.x * 4 + w;          // 0..8191
    int b = r >> 11, rr = r & 2047;
    int L = ((rr >> 7) + 1) << 7;        // padded causal length (mult of 128)
    ushort* row = S + (size_t)b * S_ * S_ + (size_t)rr * S_;

    float v[4][8];
    float mx = -1e30f;
#pragma unroll
    for (int c = 0; c < 4; ++c) {
        int j0 = c * 512 + lane * 8;
        if (j0 < L) {
            bf16x8 raw = *(const bf16x8*)(row + j0);
#pragma unroll
            for (int e = 0; e < 8; ++e) {
                float f = bf2f((ushort)raw[e]);
                v[c][e] = (j0 + e <= rr) ? f : -1e30f;
                mx = fmaxf(mx, v[c][e]);
            }
        }
    }
#pragma unroll
    for (int off = 32; off >= 1; off >>= 1) mx = fmaxf(mx, __shfl_xor(mx, off));

    float sum = 0.f;
#pragma unroll
    for (int c = 0; c < 4; ++c) {
        int j0 = c * 512 + lane * 8;
        if (j0 < L) {
#pragma unroll
            for (int e = 0; e < 8; ++e) {
                v[c][e] = (j0 + e <= rr) ? __expf(v[c][e] - mx) : 0.f;
                sum += v[c][e];
            }
        }
    }
#pragma unroll
    for (int off = 32; off >= 1; off >>= 1) sum += __shfl_xor(sum, off);
    float rinv = 1.0f / sum;

#pragma unroll
    for (int c = 0; c < 4; ++c) {
        int j0 = c * 512 + lane * 8;
        if (j0 < L) {
            bf16x8 o;
#pragma unroll
            for (int e = 0; e < 8; ++e) o[e] = (short)f2bf(v[c][e] * rinv);
            *(bf16x8*)(row + j0) = o;
        }
    }
}

// ---------------- PV: O[b][m][n] = sum_k P[b][m][k] * Vt[b][n][k] ---------
// bm sequence pairs heavy+light {15,0,14,1,...} so each XCD chunk (64 blocks
// = 8 seq entries x 8 bn) carries equal causal work (272 K-tiles/chunk).
__global__ __launch_bounds__(256) void gemm_pv(
    const ushort* __restrict__ Pb, const ushort* __restrict__ Vt,
    float* __restrict__ Out) {
    int l = xcd_swz(blockIdx.x, 512);
    int bn = l & 7;
    int r2 = l >> 3;
    int i_ = r2 & 15;
    int b  = r2 >> 4;
    int bm = (i_ & 1) ? (i_ >> 1) : (15 - (i_ >> 1));
    __shared__ ushort sm[3 * 8192];
    f32x4 acc[4][4] = {};
    const ushort* Ag = Pb + (size_t)b * S_ * S_ + (size_t)bm * 128 * S_;
    const ushort* Bg = Vt + (size_t)b * D_ * S_ + (size_t)bn * 128 * S_;
    int nk = (bm + 1) * 4;               // causal K extent: (bm+1)*128 / 32
    mm_pipe(Ag, S_, Bg, S_, nk, sm, acc);

    const int lane = threadIdx.x & 63;
    const int wid = threadIdx.x >> 6;
    const int wr = wid >> 1, wc = wid & 1;
    const int ro = lane & 15;
    const int g = lane >> 4;
    float* Crow = Out + (size_t)b * S_ * D_;
#pragma unroll
    for (int i = 0; i < 4; ++i)
#pragma unroll
        for (int j = 0; j < 4; ++j)
#pragma unroll
            for (int q = 0; q < 4; ++q) {
                int row = bm * 128 + wr * 64 + i * 16 + (g << 2) + q;
                int col = bn * 128 + wc * 64 + j * 16 + ro;
                Crow[(size_t)row * D_ + col] = acc[i][j][q];
            }
}

extern "C" void kernel_launch(void* const* d_in, const int* in_sizes, int n_in,
                              void* d_out, int out_size, void* d_ws, size_t ws_size,
                              hipStream_t stream) {
    const float* x  = (const float*)d_in[0];
    const float* Wq = (const float*)d_in[1];
    const float* Wk = (const float*)d_in[2];
    const float* Wv = (const float*)d_in[3];
    float* out = (float*)d_out;

    char* ws = (char*)d_ws;
    ushort* xb = (ushort*)(ws);                          // 16 MB
    ushort* Wb = (ushort*)(ws + (16u << 20));            //  6 MB
    ushort* Qb = (ushort*)(ws + (22u << 20));            // 16 MB
    ushort* Kb = (ushort*)(ws + (38u << 20));            // 16 MB
    ushort* Vt = (ushort*)(ws + (54u << 20));            // 16 MB (transposed)
    ushort* Sb = (ushort*)(ws + (70u << 20));            // 32 MB (S then P)

    // 1) single fused cast
    cast_all<<<2048, 256, 0, stream>>>(x, Wq, Wk, Wv, xb, Wb);

    // 2) QKV projection (z: 0=Q scaled, 1=K, 2=V^T), 1536 blocks
    gemm_qkv<<<3 * 64 * 8, 256, 0, stream>>>(xb, Wb, Qb, Kb, Vt);

    // 3) scores, compact lower-tri grid, 544 blocks
    gemm_scores<<<4 * 136, 256, 0, stream>>>(Qb, Kb, Sb);

    // 4) causal softmax in place (1 wave per row)
    softmax_causal<<<MTOT / 4, 256, 0, stream>>>(Sb);

    // 5) PV, balanced heavy/light pairing, 512 blocks
    gemm_pv<<<512, 256, 0, stream>>>(Sb, Vt, out);
}

// Round 6
// 216.757 us; speedup vs baseline: 1.3033x; 1.0289x over previous
//
#include <hip/hip_runtime.h>

typedef unsigned int uint;
typedef unsigned short ushort;
typedef __attribute__((ext_vector_type(8))) short bf16x8;
typedef __attribute__((ext_vector_type(4))) float f32x4;
typedef __attribute__((ext_vector_type(4))) float float4v;
typedef __attribute__((ext_vector_type(4))) ushort ushort4v;
typedef __attribute__((ext_vector_type(8))) ushort ushort8v;

#define B_ 4
#define S_ 2048
#define D_ 1024
#define MTOT (B_ * S_)   // 8192

__device__ __forceinline__ ushort f2bf(float f) {
    uint u = __builtin_bit_cast(uint, f);
    u = (u + 0x7FFFu + ((u >> 16) & 1u)) >> 16;   // RNE
    return (ushort)u;
}
__device__ __forceinline__ float bf2f(ushort h) {
    uint u = ((uint)h) << 16;
    return __builtin_bit_cast(float, u);
}

__device__ __forceinline__ void gload_lds16(const ushort* g, ushort* l) {
    __builtin_amdgcn_global_load_lds(
        (const __attribute__((address_space(1))) void*)g,
        (__attribute__((address_space(3))) void*)l, 16, 0, 0);
}

// T1 bijective XCD swizzle (nwg % 8 == 0 for all our grids).
__device__ __forceinline__ int xcd_swz(int bid, int nwg) {
    int cpx = nwg >> 3;
    return (bid & 7) * cpx + (bid >> 3);
}

// ---------------- fused cast: x (8M) + Wq/Wk/Wv (1M each) -> bf16 ----------
#define XU (MTOT * D_ / 4)
#define WU (D_ * D_ / 4)
__global__ void cast_all(const float* __restrict__ x,
                         const float* __restrict__ wq,
                         const float* __restrict__ wk,
                         const float* __restrict__ wv,
                         ushort* __restrict__ xb, ushort* __restrict__ wb) {
    int i = blockIdx.x * blockDim.x + threadIdx.x;
    int stride = gridDim.x * blockDim.x;
    for (; i < XU + 3 * WU; i += stride) {
        const float* src;
        ushort* dst;
        if (i < XU) { src = x + (size_t)i * 4; dst = xb + (size_t)i * 4; }
        else {
            int j = i - XU;
            int z = j / WU, o = j % WU;
            const float* w = (z == 0) ? wq : (z == 1) ? wk : wv;
            src = w + (size_t)o * 4;
            dst = wb + (size_t)z * D_ * D_ + (size_t)o * 4;
        }
        float4v f = *(const float4v*)src;
        ushort4v h;
        h.x = f2bf(f.x); h.y = f2bf(f.y); h.z = f2bf(f.z); h.w = f2bf(f.w);
        *(ushort4v*)dst = h;
    }
}

// ================= 256x256 deep-pipe core: 512 thr / 8 waves ==============
// BK=32; wave tile 128x64 (acc[8][4]); ring-3 K-tile LDS buffers (32KB each,
// A[256][32] + B[256][32]); staged 2 tiles ahead; counted vmcnt(4) once per
// tile (never 0 in steady state); swizzle LDS[r][u] = G[r][u ^ ((r>>1)&3)]
// on both source and ds_read (rule #21; verified R2: conflicts 6.3M -> 0).
__device__ __forceinline__ void stage_pair(const ushort* __restrict__ M, int ld,
                                           int k0, ushort* dst, int t) {
    int rl = t >> 2;                                  // row 0..127 (half 0)
    int c = (((t & 3) ^ ((t >> 3) & 3)) << 3) + k0;   // swizzled source col
    int wub = (t & 0x1C0) * 8;                        // wave-uniform base
    gload_lds16(M + (size_t)rl * ld + c, dst + wub);
    gload_lds16(M + (size_t)(rl + 128) * ld + c, dst + 4096 + wub);
}

__device__ __forceinline__ f32x4 MFMA(bf16x8 a, bf16x8 b, f32x4 c) {
    return __builtin_amdgcn_mfma_f32_16x16x32_bf16(a, b, c, 0, 0, 0);
}

// nt >= 2 required (always 32 here).
__device__ __forceinline__ void mm256(const ushort* __restrict__ Ag, int lda,
                                      const ushort* __restrict__ Bg, int ldb,
                                      int nt, ushort* sm, f32x4 acc[8][4]) {
    const int t = threadIdx.x;
    const int lane = t & 63;
    const int wid = t >> 6;
    const int wr = wid >> 2, wc = wid & 3;
    const int ro = lane & 15;
    const int g = lane >> 4;
    const int uo = ((g ^ ((ro >> 1) & 3)) << 3);

    // prologue: tiles 0,1 -> bufs 0,1
    stage_pair(Ag, lda, 0, sm, t);
    stage_pair(Bg, ldb, 0, sm + 8192, t);
    stage_pair(Ag, lda, 32, sm + 16384, t);
    stage_pair(Bg, ldb, 32, sm + 16384 + 8192, t);
    asm volatile("s_waitcnt vmcnt(4)" ::: "memory");  // tile 0 landed
    __builtin_amdgcn_s_barrier();
    asm volatile("" ::: "memory");

    bf16x8 af[4], bf[4];
    int sbuf = 0;
    for (int kt = 0; kt < nt; ++kt) {
        const ushort* As = sm + sbuf * 16384;
        const ushort* Bs = As + 8192;
        int nbuf = (sbuf == 2) ? 0 : sbuf + 1;
        int pbuf = (nbuf == 2) ? 0 : nbuf + 1;        // target for tile kt+2
        ushort* stb = sm + pbuf * 16384;
        bool do_stage = (kt + 2 < nt);

        // ---- phase 0: i 0..3 ----
#pragma unroll
        for (int i = 0; i < 4; ++i)
            af[i] = *(const bf16x8*)(As + (wr * 128 + i * 16 + ro) * 32 + uo);
#pragma unroll
        for (int j = 0; j < 4; ++j)
            bf[j] = *(const bf16x8*)(Bs + (wc * 64 + j * 16 + ro) * 32 + uo);
        if (do_stage) stage_pair(Ag, lda, (kt + 2) * 32, stb, t);
        asm volatile("" ::: "memory");
        __builtin_amdgcn_s_barrier();                 // mid barrier (rhythm)
        asm volatile("" ::: "memory");
        __builtin_amdgcn_s_setprio(1);
#pragma unroll
        for (int i = 0; i < 4; ++i)
#pragma unroll
            for (int j = 0; j < 4; ++j)
                acc[i][j] = MFMA(af[i], bf[j], acc[i][j]);
        __builtin_amdgcn_s_setprio(0);

        // ---- phase 1: i 4..7 (B reused in regs) ----
#pragma unroll
        for (int i = 0; i < 4; ++i)
            af[i] = *(const bf16x8*)(As + (wr * 128 + (i + 4) * 16 + ro) * 32 + uo);
        if (do_stage) stage_pair(Bg, ldb, (kt + 2) * 32, stb + 8192, t);
        asm volatile("" ::: "memory");
        __builtin_amdgcn_s_setprio(1);
#pragma unroll
        for (int i = 0; i < 4; ++i)
#pragma unroll
            for (int j = 0; j < 4; ++j)
                acc[i + 4][j] = MFMA(af[i], bf[j], acc[i + 4][j]);
        __builtin_amdgcn_s_setprio(0);
        // tile-boundary: ensure tile kt+1 landed everywhere, publish, WAR.
        if (kt + 1 < nt) {
            if (do_stage) asm volatile("s_waitcnt vmcnt(4)" ::: "memory");
            else          asm volatile("s_waitcnt vmcnt(0)" ::: "memory");
        }
        asm volatile("" ::: "memory");
        __builtin_amdgcn_s_barrier();                 // end barrier
        asm volatile("" ::: "memory");
        sbuf = nbuf;
    }
}

// ---------------- Q,K projection on the 256-core ---------------------------
// grid 256 = exactly 1 block/CU. logical l: z(2) x bm(32) x bn(4), bn fastest.
__global__ __launch_bounds__(512, 2) void gemm_qk256(
    const ushort* __restrict__ xb, const ushort* __restrict__ Wb,
    ushort* __restrict__ Qb, ushort* __restrict__ Kb) {
    __shared__ ushort sm[3 * 16384];
    int l = xcd_swz(blockIdx.x, 256);
    int bn = l & 3;
    int bm = (l >> 2) & 31;
    int z = l >> 7;
    f32x4 acc[8][4] = {};
    const ushort* Ag = xb + (size_t)bm * 256 * D_;
    const ushort* Bg = Wb + (size_t)z * D_ * D_ + (size_t)bn * 256 * D_;
    mm256(Ag, D_, Bg, D_, D_ / 32, sm, acc);

    const int t = threadIdx.x;
    const int lane = t & 63;
    const int wid = t >> 6;
    const int wr = wid >> 2, wc = wid & 3;
    const int ro = lane & 15;
    const int g = lane >> 4;
    const float scale = (z == 0) ? 0.03125f : 1.0f;
    ushort* Dst = (z == 0) ? Qb : Kb;
#pragma unroll
    for (int i = 0; i < 8; ++i)
#pragma unroll
        for (int j = 0; j < 4; ++j)
#pragma unroll
            for (int q = 0; q < 4; ++q) {
                int row = bm * 256 + wr * 128 + i * 16 + (g << 2) + q;
                int col = bn * 256 + wc * 64 + j * 16 + ro;
                Dst[(size_t)row * D_ + col] = f2bf(acc[i][j][q] * scale);
            }
}

// ---------------- scores on the 256-core -----------------------------------
// compact lower-tri 256-tiles: 36/batch x 4 = 144 blocks, all K=1024.
__global__ __launch_bounds__(512, 2) void gemm_scores256(
    const ushort* __restrict__ Qb, const ushort* __restrict__ Kb,
    ushort* __restrict__ Sb) {
    __shared__ ushort sm[3 * 16384];
    int l = xcd_swz(blockIdx.x, 144);
    int b = l / 36;
    int tt = l - b * 36;
    int bm = 0;
    while (((bm + 1) * (bm + 2)) / 2 <= tt) ++bm;     // <= 7 iters
    int bn = tt - (bm * (bm + 1)) / 2;
    f32x4 acc[8][4] = {};
    const ushort* Ag = Qb + (size_t)b * S_ * D_ + (size_t)bm * 256 * D_;
    const ushort* Bg = Kb + (size_t)b * S_ * D_ + (size_t)bn * 256 * D_;
    mm256(Ag, D_, Bg, D_, D_ / 32, sm, acc);

    const int t = threadIdx.x;
    const int lane = t & 63;
    const int wid = t >> 6;
    const int wr = wid >> 2, wc = wid & 3;
    const int ro = lane & 15;
    const int g = lane >> 4;
    ushort* Crow = Sb + (size_t)b * S_ * S_;
#pragma unroll
    for (int i = 0; i < 8; ++i)
#pragma unroll
        for (int j = 0; j < 4; ++j)
#pragma unroll
            for (int q = 0; q < 4; ++q) {
                int row = bm * 256 + wr * 128 + i * 16 + (g << 2) + q;
                int col = bn * 256 + wc * 64 + j * 16 + ro;
                Crow[(size_t)row * S_ + col] = f2bf(acc[i][j][q]);
            }
}

// ================= 128x128 ring core (R5, verified) ========================
__device__ __forceinline__ void stage_tile(const ushort* __restrict__ Ag, int lda,
                                           const ushort* __restrict__ Bg, int ldb,
                                           int k0, ushort* slot, int t) {
#pragma unroll
    for (int i = 0; i < 2; ++i) {
        int U = i * 256 + t;
        int r = U >> 2;
        int u = U & 3;
        int c = ((u ^ ((r >> 1) & 3)) << 3);
        int ldsbase = i * 2048 + (t & 192) * 8;
        gload_lds16(Ag + (size_t)r * lda + (k0 + c), slot + ldsbase);
        gload_lds16(Bg + (size_t)r * ldb + (k0 + c), slot + 4096 + ldsbase);
    }
}

__device__ __forceinline__ void mm_pipe(const ushort* __restrict__ Ag, int lda,
                                        const ushort* __restrict__ Bg, int ldb,
                                        int nk, ushort* sm, f32x4 acc[4][4]) {
    const int t = threadIdx.x;
    const int lane = t & 63;
    const int wid = t >> 6;
    const int wr = wid >> 1, wc = wid & 1;
    const int ro = lane & 15;
    const int g = lane >> 4;
    const int uo = ((g ^ ((ro >> 1) & 3)) << 3);

#pragma unroll
    for (int p = 0; p < 2; ++p)
        if (p < nk) stage_tile(Ag, lda, Bg, ldb, p * 32, sm + p * 8192, t);

    int slot_n = 2, slot_c = 0;
    for (int ks = 0; ks < nk; ++ks) {
        if (ks + 2 < nk)
            stage_tile(Ag, lda, Bg, ldb, (ks + 2) * 32, sm + slot_n * 8192, t);
        int ahead = nk - 1 - ks;
        if (ahead >= 2)      asm volatile("s_waitcnt vmcnt(8)" ::: "memory");
        else if (ahead == 1) asm volatile("s_waitcnt vmcnt(4)" ::: "memory");
        else                 asm volatile("s_waitcnt vmcnt(0)" ::: "memory");
        __builtin_amdgcn_s_barrier();
        asm volatile("" ::: "memory");

        const ushort* As = sm + slot_c * 8192;
        const ushort* Bs = As + 4096;
        bf16x8 af[4], bfr[4];
#pragma unroll
        for (int i = 0; i < 4; ++i)
            af[i] = *(const bf16x8*)(As + (wr * 64 + i * 16 + ro) * 32 + uo);
#pragma unroll
        for (int j = 0; j < 4; ++j)
            bfr[j] = *(const bf16x8*)(Bs + (wc * 64 + j * 16 + ro) * 32 + uo);
        __builtin_amdgcn_s_setprio(1);
#pragma unroll
        for (int i = 0; i < 4; ++i)
#pragma unroll
            for (int j = 0; j < 4; ++j)
                acc[i][j] = MFMA(af[i], bfr[j], acc[i][j]);
        __builtin_amdgcn_s_setprio(0);
        asm volatile("" ::: "memory");
        __builtin_amdgcn_s_barrier();
        slot_c = (slot_c == 2) ? 0 : slot_c + 1;
        slot_n = (slot_n == 2) ? 0 : slot_n + 1;
    }
}

// ---------------- V projection (stored transposed), 128-core --------------
__global__ __launch_bounds__(256) void gemm_v(
    const ushort* __restrict__ xb, const ushort* __restrict__ Wb,
    ushort* __restrict__ Vt) {
    __shared__ ushort sm[3 * 8192];
    int l = xcd_swz(blockIdx.x, 512);
    int bn = l & 7;
    int bm = (l >> 3) & 63;
    f32x4 acc[4][4] = {};
    const ushort* Ag = xb + (size_t)bm * 128 * D_;
    const ushort* Bg = Wb + (size_t)2 * D_ * D_ + (size_t)bn * 128 * D_;
    mm_pipe(Ag, D_, Bg, D_, D_ / 32, sm, acc);

    const int t = threadIdx.x;
    const int lane = t & 63;
    const int wid = t >> 6;
    const int wr = wid >> 1, wc = wid & 1;
    const int ro = lane & 15;
    const int g = lane >> 4;

    ushort* smT = sm;                    // 32KB scratch (fits in 48KB)
    __syncthreads();
#pragma unroll
    for (int i = 0; i < 4; ++i)
#pragma unroll
        for (int j = 0; j < 4; ++j) {
            int C = wc * 64 + j * 16 + ro;
            int ru = wr * 16 + i * 4 + g;
            ushort4v pk;
            pk.x = f2bf(acc[i][j][0]);
            pk.y = f2bf(acc[i][j][1]);
            pk.z = f2bf(acc[i][j][2]);
            pk.w = f2bf(acc[i][j][3]);
            *(ushort4v*)(smT + C * 128 + ((ru ^ (C & 31)) << 2)) = pk;
        }
    __syncthreads();
    int b = (bm * 128) >> 11;
    int s0 = (bm * 128) & 2047;
#pragma unroll
    for (int it = 0; it < 8; ++it) {
        int F = it * 256 + t;
        int o = F >> 4;
        int sc = F & 15;
        ushort4v u0 = *(const ushort4v*)(smT + o * 128 + (((sc * 2) ^ (o & 31)) << 2));
        ushort4v u1 = *(const ushort4v*)(smT + o * 128 + (((sc * 2 + 1) ^ (o & 31)) << 2));
        ushort8v v8;
        v8[0] = u0.x; v8[1] = u0.y; v8[2] = u0.z; v8[3] = u0.w;
        v8[4] = u1.x; v8[5] = u1.y; v8[6] = u1.z; v8[7] = u1.w;
        *(ushort8v*)(Vt + (size_t)b * D_ * S_ +
                     (size_t)(bn * 128 + o) * S_ + s0 + sc * 8) = v8;
    }
}

// ---------------- causal row softmax, in place, bf16, 1 wave/row ----------
__global__ __launch_bounds__(256) void softmax_causal(ushort* __restrict__ S) {
    int t = threadIdx.x;
    int lane = t & 63, w = t >> 6;
    int r = blockIdx.x * 4 + w;
    int b = r >> 11, rr = r & 2047;
    int L = ((rr >> 7) + 1) << 7;
    ushort* row = S + (size_t)b * S_ * S_ + (size_t)rr * S_;

    float v[4][8];
    float mx = -1e30f;
#pragma unroll
    for (int c = 0; c < 4; ++c) {
        int j0 = c * 512 + lane * 8;
        if (j0 < L) {
            bf16x8 raw = *(const bf16x8*)(row + j0);
#pragma unroll
            for (int e = 0; e < 8; ++e) {
                float f = bf2f((ushort)raw[e]);
                v[c][e] = (j0 + e <= rr) ? f : -1e30f;
                mx = fmaxf(mx, v[c][e]);
            }
        }
    }
#pragma unroll
    for (int off = 32; off >= 1; off >>= 1) mx = fmaxf(mx, __shfl_xor(mx, off));

    float sum = 0.f;
#pragma unroll
    for (int c = 0; c < 4; ++c) {
        int j0 = c * 512 + lane * 8;
        if (j0 < L) {
#pragma unroll
            for (int e = 0; e < 8; ++e) {
                v[c][e] = (j0 + e <= rr) ? __expf(v[c][e] - mx) : 0.f;
                sum += v[c][e];
            }
        }
    }
#pragma unroll
    for (int off = 32; off >= 1; off >>= 1) sum += __shfl_xor(sum, off);
    float rinv = 1.0f / sum;

#pragma unroll
    for (int c = 0; c < 4; ++c) {
        int j0 = c * 512 + lane * 8;
        if (j0 < L) {
            bf16x8 o;
#pragma unroll
            for (int e = 0; e < 8; ++e) o[e] = (short)f2bf(v[c][e] * rinv);
            *(bf16x8*)(row + j0) = o;
        }
    }
}

// ---------------- PV: O[b][m][n] = sum_k P[b][m][k] * Vt[b][n][k] ---------
__global__ __launch_bounds__(256) void gemm_pv(
    const ushort* __restrict__ Pb, const ushort* __restrict__ Vt,
    float* __restrict__ Out) {
    int l = xcd_swz(blockIdx.x, 512);
    int bn = l & 7;
    int r2 = l >> 3;
    int i_ = r2 & 15;
    int b = r2 >> 4;
    int bm = (i_ & 1) ? (i_ >> 1) : (15 - (i_ >> 1));
    __shared__ ushort sm[3 * 8192];
    f32x4 acc[4][4] = {};
    const ushort* Ag = Pb + (size_t)b * S_ * S_ + (size_t)bm * 128 * S_;
    const ushort* Bg = Vt + (size_t)b * D_ * S_ + (size_t)bn * 128 * S_;
    int nk = (bm + 1) * 4;
    mm_pipe(Ag, S_, Bg, S_, nk, sm, acc);

    const int lane = threadIdx.x & 63;
    const int wid = threadIdx.x >> 6;
    const int wr = wid >> 1, wc = wid & 1;
    const int ro = lane & 15;
    const int g = lane >> 4;
    float* Crow = Out + (size_t)b * S_ * D_;
#pragma unroll
    for (int i = 0; i < 4; ++i)
#pragma unroll
        for (int j = 0; j < 4; ++j)
#pragma unroll
            for (int q = 0; q < 4; ++q) {
                int row = bm * 128 + wr * 64 + i * 16 + (g << 2) + q;
                int col = bn * 128 + wc * 64 + j * 16 + ro;
                Crow[(size_t)row * D_ + col] = acc[i][j][q];
            }
}

extern "C" void kernel_launch(void* const* d_in, const int* in_sizes, int n_in,
                              void* d_out, int out_size, void* d_ws, size_t ws_size,
                              hipStream_t stream) {
    const float* x  = (const float*)d_in[0];
    const float* Wq = (const float*)d_in[1];
    const float* Wk = (const float*)d_in[2];
    const float* Wv = (const float*)d_in[3];
    float* out = (float*)d_out;

    char* ws = (char*)d_ws;
    ushort* xb = (ushort*)(ws);                          // 16 MB
    ushort* Wb = (ushort*)(ws + (16u << 20));            //  6 MB
    ushort* Qb = (ushort*)(ws + (22u << 20));            // 16 MB
    ushort* Kb = (ushort*)(ws + (38u << 20));            // 16 MB
    ushort* Vt = (ushort*)(ws + (54u << 20));            // 16 MB (transposed)
    ushort* Sb = (ushort*)(ws + (70u << 20));            // 32 MB (S then P)

    // 1) fused cast
    cast_all<<<2048, 256, 0, stream>>>(x, Wq, Wk, Wv, xb, Wb);

    // 2) Q,K on the 256-core (256 blocks = 1/CU, one round)
    gemm_qk256<<<256, 512, 0, stream>>>(xb, Wb, Qb, Kb);

    // 3) V on the 128-core (512 blocks), transposed store
    gemm_v<<<512, 256, 0, stream>>>(xb, Wb, Vt);

    // 4) scores on the 256-core, compact lower-tri (144 blocks)
    gemm_scores256<<<144, 512, 0, stream>>>(Qb, Kb, Sb);

    // 5) causal softmax in place
    softmax_causal<<<MTOT / 4, 256, 0, stream>>>(Sb);

    // 6) PV (128-core, balanced heavy/light pairing)
    gemm_pv<<<512, 256, 0, stream>>>(Sb, Vt, out);
}